// Round 1
// baseline (325.171 us; speedup 1.0000x reference)
//
#include <hip/hip_runtime.h>

#define IMG_W 2048
#define OUT_W 2044
#define OUT_HW (2044 * 2044)

// Pre-kernel: quantize weights to 9-bit ints, layout [kd][kh+1][kw] with
// zero rows at kh=-1 and kh=5 so the main kernel's r-loop body is uniform.
__global__ void quant_wq(const float* __restrict__ w, int* __restrict__ wqp) {
    int idx = threadIdx.x;
    if (idx < 105) {
        int kd = idx / 35, rem = idx % 35;
        int khp = rem / 5, kw = rem % 5;
        int kh = khp - 1;
        int val = 0;
        if (kh >= 0 && kh < 5) val = (int)rintf(w[(kd * 5 + kh) * 5 + kw] * 511.0f);
        wqp[idx] = val;
    }
}

// Each thread: 2x4 (i x j) tile of output columns, all 14 d-planes.
// d-pairs packed in 16-bit fields of u32 accumulators (max 38325 < 2^16).
__global__ __launch_bounds__(256) void conv_bits(
        const int* __restrict__ x, const int* __restrict__ wqp,
        const float* __restrict__ bias, float* __restrict__ out) {
    const int lane = threadIdx.x & 63;
    const int sub  = threadIdx.x >> 6;
    const int tx = blockIdx.x * 64 + lane;   // j-tile index, 0..510
    const int ty = blockIdx.y * 4 + sub;     // i-tile index, 0..1021
    if (tx >= 511 || ty >= 1022) return;
    const int j0 = tx * 4;
    const int i0 = ty * 2;

    unsigned acc[2][4][7] = {};  // [di][dj][d-pair]

    const float b0 = bias[0];

    #pragma unroll 1           // keep body ~1.1k inst, I-cache resident
    for (int r = 0; r < 6; ++r) {
        // weights for this pixel row: kh = r - di, zero-padded table
        int wr[2][3][5];
        #pragma unroll
        for (int di = 0; di < 2; ++di) {
            const int khp = r - di + 1;  // 0..6, uniform -> s_load
            #pragma unroll
            for (int kd = 0; kd < 3; ++kd)
                #pragma unroll
                for (int kw = 0; kw < 5; ++kw)
                    wr[di][kd][kw] = wqp[kd * 35 + khp * 5 + kw];
        }
        const int* row = x + (size_t)(i0 + r) * IMG_W + j0;
        const int4 va = *(const int4*)row;        // 16B aligned (j0 % 4 == 0)
        const int4 vb = *(const int4*)(row + 4);
        const int v[8] = {va.x, va.y, va.z, va.w, vb.x, vb.y, vb.z, vb.w};
        #pragma unroll
        for (int c = 0; c < 8; ++c) {
            // D = (v<<15)|v : (D>>k)&0x10001 = bit k | bit k+1 << 16
            const unsigned uv = (unsigned)v[c];
            const unsigned long long Dv = ((unsigned long long)uv << 15) | uv;
            unsigned S[8], T[7];
            #pragma unroll
            for (int g = 0; g < 8; ++g) S[g] = (unsigned)(Dv >> (2 * g)) & 0x10001u;
            #pragma unroll
            for (int g = 0; g < 7; ++g) T[g] = (unsigned)(Dv >> (2 * g + 1)) & 0x10001u;
            #pragma unroll
            for (int di = 0; di < 2; ++di) {
                #pragma unroll
                for (int dj = 0; dj < 4; ++dj) {
                    const int kw = c - dj;
                    if (kw < 0 || kw >= 5) continue;  // compile-time
                    const unsigned w0 = (unsigned)wr[di][0][kw];
                    const unsigned w1 = (unsigned)wr[di][1][kw];
                    const unsigned w2 = (unsigned)wr[di][2][kw];
                    #pragma unroll
                    for (int p = 0; p < 7; ++p) {
                        // acc pair p covers d=2p (lo field), d=2p+1 (hi field)
                        acc[di][dj][p] += __umul24(S[p],     w0);  // kd=0: bits d..d+1
                        acc[di][dj][p] += __umul24(T[p],     w1);  // kd=1: bits d+1..d+2
                        acc[di][dj][p] += __umul24(S[p + 1], w2);  // kd=2: bits d+2..d+3
                    }
                }
            }
        }
    }

    const float scale = 1.0f / 511.0f;
    #pragma unroll
    for (int di = 0; di < 2; ++di) {
        const int i = i0 + di;
        #pragma unroll
        for (int p = 0; p < 7; ++p) {
            #pragma unroll
            for (int h = 0; h < 2; ++h) {
                const int d = 2 * p + h;
                unsigned f0 = h ? (acc[di][0][p] >> 16) : (acc[di][0][p] & 0xFFFFu);
                unsigned f1 = h ? (acc[di][1][p] >> 16) : (acc[di][1][p] & 0xFFFFu);
                unsigned f2 = h ? (acc[di][2][p] >> 16) : (acc[di][2][p] & 0xFFFFu);
                unsigned f3 = h ? (acc[di][3][p] >> 16) : (acc[di][3][p] & 0xFFFFu);
                float4 o;
                o.x = fmaf((float)f0, scale, b0);
                o.y = fmaf((float)f1, scale, b0);
                o.z = fmaf((float)f2, scale, b0);
                o.w = fmaf((float)f3, scale, b0);
                *(float4*)(out + (size_t)d * OUT_HW + (size_t)i * OUT_W + j0) = o;
            }
        }
    }
}

extern "C" void kernel_launch(void* const* d_in, const int* in_sizes, int n_in,
                              void* d_out, int out_size, void* d_ws, size_t ws_size,
                              hipStream_t stream) {
    const int* x      = (const int*)d_in[0];
    const float* w    = (const float*)d_in[1];
    const float* bias = (const float*)d_in[2];
    float* out        = (float*)d_out;
    int* wqp          = (int*)d_ws;   // 105 ints of scratch
    quant_wq<<<1, 128, 0, stream>>>(w, wqp);
    conv_bits<<<dim3(8, 256), 256, 0, stream>>>(x, wqp, bias, out);
}

// Round 2
// 272.804 us; speedup vs baseline: 1.1920x; 1.1920x over previous
//
#include <hip/hip_runtime.h>

#define IMG_W 2048
#define OUT_W 2044
#define OUT_HW (2044 * 2044)

// Pre-kernel: quantize weights to 8-bit ints and pack per (khp, kw) the
// kd-triple into a dot4 weight word: W0 = w0 | w1<<8 | w2<<16 (even d),
// W1 = W0<<8 (odd d). khp = kh+1 in [0,7), zero rows at khp=0 and khp>=6.
__global__ void quant_wq(const float* __restrict__ w, unsigned* __restrict__ wt) {
    int idx = threadIdx.x;           // khp*5 + kw
    if (idx < 35) {
        int khp = idx / 5, kw = idx % 5;
        int kh = khp - 1;
        unsigned w0 = 0, w1 = 0, w2 = 0;
        if (kh >= 0 && kh < 5) {
            w0 = (unsigned)(int)rintf(w[(0 * 5 + kh) * 5 + kw] * 255.0f);
            w1 = (unsigned)(int)rintf(w[(1 * 5 + kh) * 5 + kw] * 255.0f);
            w2 = (unsigned)(int)rintf(w[(2 * 5 + kh) * 5 + kw] * 255.0f);
        }
        unsigned W0 = w0 | (w1 << 8) | (w2 << 16);
        wt[idx * 2]     = W0;
        wt[idx * 2 + 1] = W0 << 8;
    }
}

// Each thread: 2 (i) x 4 (j) tile of output columns, all 14 d-planes.
// P[t] = bit-planes 2t..2t+3 of a pixel spread into byte lanes; one
// v_dot4_u32_u8 then does all 3 kd-taps for one (d, kh, kw).
__global__ __launch_bounds__(256) void conv_dot(
        const int* __restrict__ x, const unsigned* __restrict__ wt,
        const float* __restrict__ bias, float* __restrict__ out) {
    const int lane = threadIdx.x & 63;
    const int sub  = threadIdx.x >> 6;
    const int tx = blockIdx.x * 64 + lane;   // j-tile 0..510
    const int ty = blockIdx.y * 4 + sub;     // i-tile 0..1021
    if (tx >= 511 || ty >= 1022) return;
    const int j0 = tx * 4;
    const int i0 = ty * 2;

    unsigned acc[2][4][14] = {};   // [di][dj][d]
    const float b0 = bias[0];

    #pragma unroll 1               // keep body I-cache resident
    for (int r = 0; r < 6; ++r) {
        const int* row = x + (size_t)(i0 + r) * IMG_W + j0;
        const int4 va = *(const int4*)row;           // j0 % 4 == 0 -> 16B aligned
        const int4 vb = *(const int4*)(row + 4);
        const unsigned v[8] = {(unsigned)va.x, (unsigned)va.y, (unsigned)va.z, (unsigned)va.w,
                               (unsigned)vb.x, (unsigned)vb.y, (unsigned)vb.z, (unsigned)vb.w};

        // weight words for this input row: di=0 -> khp=r+1, di=1 -> khp=r
        unsigned Wa[5][2], Wb[5][2];
        #pragma unroll
        for (int kw = 0; kw < 5; ++kw) {
            Wa[kw][0] = wt[((r + 1) * 5 + kw) * 2];
            Wa[kw][1] = wt[((r + 1) * 5 + kw) * 2 + 1];
            Wb[kw][0] = wt[(r * 5 + kw) * 2];
            Wb[kw][1] = wt[(r * 5 + kw) * 2 + 1];
        }
        const bool doA = (r <= 4);   // kh = r   in [0,5)
        const bool doB = (r >= 1);   // kh = r-1 in [0,5)

        #pragma unroll
        for (int c = 0; c < 8; ++c) {
            unsigned P[7];
            #pragma unroll
            for (int t = 0; t < 7; ++t)
                P[t] = __umul24((v[c] >> (2 * t)) & 0xFu, 0x00204081u) & 0x01010101u;
            if (doA) {
                #pragma unroll
                for (int dj = 0; dj < 4; ++dj) {
                    const int kw = c - dj;
                    if (kw < 0 || kw > 4) continue;          // compile-time
                    #pragma unroll
                    for (int t = 0; t < 7; ++t) {
                        acc[0][dj][2 * t]     = __builtin_amdgcn_udot4(P[t], Wa[kw][0], acc[0][dj][2 * t], false);
                        acc[0][dj][2 * t + 1] = __builtin_amdgcn_udot4(P[t], Wa[kw][1], acc[0][dj][2 * t + 1], false);
                    }
                }
            }
            if (doB) {
                #pragma unroll
                for (int dj = 0; dj < 4; ++dj) {
                    const int kw = c - dj;
                    if (kw < 0 || kw > 4) continue;
                    #pragma unroll
                    for (int t = 0; t < 7; ++t) {
                        acc[1][dj][2 * t]     = __builtin_amdgcn_udot4(P[t], Wb[kw][0], acc[1][dj][2 * t], false);
                        acc[1][dj][2 * t + 1] = __builtin_amdgcn_udot4(P[t], Wb[kw][1], acc[1][dj][2 * t + 1], false);
                    }
                }
            }
        }
    }

    const float scale = 1.0f / 255.0f;
    #pragma unroll
    for (int di = 0; di < 2; ++di) {
        const int i = i0 + di;
        #pragma unroll
        for (int d = 0; d < 14; ++d) {
            float4 o;
            o.x = fmaf((float)acc[di][0][d], scale, b0);
            o.y = fmaf((float)acc[di][1][d], scale, b0);
            o.z = fmaf((float)acc[di][2][d], scale, b0);
            o.w = fmaf((float)acc[di][3][d], scale, b0);
            *(float4*)(out + (size_t)d * OUT_HW + (size_t)i * OUT_W + j0) = o;
        }
    }
}

extern "C" void kernel_launch(void* const* d_in, const int* in_sizes, int n_in,
                              void* d_out, int out_size, void* d_ws, size_t ws_size,
                              hipStream_t stream) {
    const int* x      = (const int*)d_in[0];
    const float* w    = (const float*)d_in[1];
    const float* bias = (const float*)d_in[2];
    float* out        = (float*)d_out;
    unsigned* wt      = (unsigned*)d_ws;   // 70 u32 of scratch
    quant_wq<<<1, 64, 0, stream>>>(w, wt);
    conv_dot<<<dim3(8, 256), 256, 0, stream>>>(x, wt, bias, out);
}

// Round 3
// 265.314 us; speedup vs baseline: 1.2256x; 1.0282x over previous
//
#include <hip/hip_runtime.h>

#define IMG_W 2048
#define OUT_W 2044
#define OUT_HW (2044 * 2044)

// Pre-kernel: quantize weights to 8-bit and pack per (kh, kw) the kd-triple
// into dot4 weight words: W0 = w0 | w1<<8 | w2<<16 (even d, P byte lanes 0-2),
// W1 = W0 << 8 (odd d, P byte lanes 1-3). Layout wt[(kh*5+kw)*2 + parity].
__global__ void quant_wq(const float* __restrict__ w, unsigned* __restrict__ wt) {
    int idx = threadIdx.x;           // kh*5 + kw
    if (idx < 25) {
        int kh = idx / 5, kw = idx % 5;
        unsigned w0 = (unsigned)(int)rintf(w[(0 * 5 + kh) * 5 + kw] * 255.0f);
        unsigned w1 = (unsigned)(int)rintf(w[(1 * 5 + kh) * 5 + kw] * 255.0f);
        unsigned w2 = (unsigned)(int)rintf(w[(2 * 5 + kh) * 5 + kw] * 255.0f);
        unsigned W0 = w0 | (w1 << 8) | (w2 << 16);
        wt[idx * 2]     = W0;
        wt[idx * 2 + 1] = W0 << 8;
    }
}

// One half of the d-axis per workgroup (HALF=0: d 0..6 uses bit-spreads
// t=0..3; HALF=1: d 7..13 uses t=3..6). Fully unrolled r-loop so all weight
// words are compile-time-indexed -> SGPRs via s_load.
template<int HALF>
__device__ __forceinline__ void conv_body(
        const int* __restrict__ x, const unsigned* __restrict__ wt,
        const float* __restrict__ bias, float* __restrict__ out) {
    const int lane = threadIdx.x & 63;
    const int sub  = threadIdx.x >> 6;
    const int tx = blockIdx.x * 64 + lane;   // j-tile 0..510
    const int ty = blockIdx.y * 4 + sub;     // i-tile 0..1021
    if (tx >= 511 || ty >= 1022) return;
    const int j0 = tx * 4;
    const int i0 = ty * 2;

    // Uniform weight words -> SGPRs (compile-time offsets from kernarg ptr).
    unsigned W0[5][5], W1[5][5];
    #pragma unroll
    for (int kh = 0; kh < 5; ++kh)
        #pragma unroll
        for (int kw = 0; kw < 5; ++kw) {
            W0[kh][kw] = wt[(kh * 5 + kw) * 2];
            W1[kh][kw] = wt[(kh * 5 + kw) * 2 + 1];
        }

    unsigned acc[2][4][7] = {};   // [di][dj][local d]
    const float b0 = bias[0];

    #pragma unroll
    for (int r = 0; r < 6; ++r) {
        const int* row = x + (size_t)(i0 + r) * IMG_W + j0;
        const int4 va = *(const int4*)row;        // j0 % 4 == 0 -> 16B aligned
        const int4 vb = *(const int4*)(row + 4);
        const unsigned v[8] = {(unsigned)va.x, (unsigned)va.y, (unsigned)va.z, (unsigned)va.w,
                               (unsigned)vb.x, (unsigned)vb.y, (unsigned)vb.z, (unsigned)vb.w};
        #pragma unroll
        for (int c = 0; c < 8; ++c) {
            // P[u] = bits (2t..2t+3) of pixel, spread to byte lanes; t = t0+u
            unsigned P[4];
            #pragma unroll
            for (int u = 0; u < 4; ++u) {
                const int t = (HALF ? 3 : 0) + u;
                P[u] = __umul24((v[c] >> (2 * t)) & 0xFu, 0x00204081u) & 0x01010101u;
            }
            #pragma unroll
            for (int di = 0; di < 2; ++di) {
                const int kh = r - di;
                if (kh < 0 || kh > 4) continue;       // compile-time
                #pragma unroll
                for (int dj = 0; dj < 4; ++dj) {
                    const int kw = c - dj;
                    if (kw < 0 || kw > 4) continue;   // compile-time
                    const unsigned w0 = W0[kh][kw];
                    const unsigned w1 = W1[kh][kw];
                    if (HALF == 0) {
                        // even d=2u -> local 2u ; odd d=2u+1 -> local 2u+1
                        #pragma unroll
                        for (int u = 0; u < 4; ++u)
                            acc[di][dj][2 * u] = __builtin_amdgcn_udot4(P[u], w0, acc[di][dj][2 * u], false);
                        #pragma unroll
                        for (int u = 0; u < 3; ++u)
                            acc[di][dj][2 * u + 1] = __builtin_amdgcn_udot4(P[u], w1, acc[di][dj][2 * u + 1], false);
                    } else {
                        // t = u+3: odd d=2t+1=7+2u -> local 2u ; even d=2t=6+2u -> local 2u-1
                        #pragma unroll
                        for (int u = 0; u < 4; ++u)
                            acc[di][dj][2 * u] = __builtin_amdgcn_udot4(P[u], w1, acc[di][dj][2 * u], false);
                        #pragma unroll
                        for (int u = 1; u < 4; ++u)
                            acc[di][dj][2 * u - 1] = __builtin_amdgcn_udot4(P[u], w0, acc[di][dj][2 * u - 1], false);
                    }
                }
            }
        }
    }

    const float scale = 1.0f / 255.0f;
    #pragma unroll
    for (int di = 0; di < 2; ++di) {
        const int i = i0 + di;
        #pragma unroll
        for (int ld = 0; ld < 7; ++ld) {
            const int d = (HALF ? 7 : 0) + ld;
            float4 o;
            o.x = fmaf((float)acc[di][0][ld], scale, b0);
            o.y = fmaf((float)acc[di][1][ld], scale, b0);
            o.z = fmaf((float)acc[di][2][ld], scale, b0);
            o.w = fmaf((float)acc[di][3][ld], scale, b0);
            *(float4*)(out + (size_t)d * OUT_HW + (size_t)i * OUT_W + j0) = o;
        }
    }
}

__global__ __launch_bounds__(256) void conv_dot(
        const int* __restrict__ x, const unsigned* __restrict__ wt,
        const float* __restrict__ bias, float* __restrict__ out) {
    if (blockIdx.z == 0) conv_body<0>(x, wt, bias, out);
    else                 conv_body<1>(x, wt, bias, out);
}

extern "C" void kernel_launch(void* const* d_in, const int* in_sizes, int n_in,
                              void* d_out, int out_size, void* d_ws, size_t ws_size,
                              hipStream_t stream) {
    const int* x      = (const int*)d_in[0];
    const float* w    = (const float*)d_in[1];
    const float* bias = (const float*)d_in[2];
    float* out        = (float*)d_out;
    unsigned* wt      = (unsigned*)d_ws;   // 50 u32 of scratch
    quant_wq<<<1, 64, 0, stream>>>(w, wt);
    conv_dot<<<dim3(8, 256, 2), 256, 0, stream>>>(x, wt, bias, out);
}